// Round 8
// baseline (5531.094 us; speedup 1.0000x reference)
//
#include <hip/hip_runtime.h>

typedef _Float16 half8 __attribute__((ext_vector_type(8)));
typedef float floatx4 __attribute__((ext_vector_type(4)));
typedef float floatx2 __attribute__((ext_vector_type(2)));
typedef unsigned long long u64;

#define T_STEPS 512
#define IN_DIM 256
#define HID 512
#define RING 8
#define SPIN_BUDGET 4000

__device__ inline float sig_f(float x) { return 1.f / (1.f + __expf(-x)); }
__device__ inline float tanh_f(float x) {
  float t = __expf(-2.f * fabsf(x));
  return copysignf((1.f - t) / (1.f + t), x);
}

// ---- LLC-coherent (agent-scope) accessors — proven in R3 ----
__device__ inline u64 cload64(const _Float16* p) {
  return __hip_atomic_load((const u64*)p, __ATOMIC_RELAXED, __HIP_MEMORY_SCOPE_AGENT);
}
__device__ inline half8 cload_h8(const _Float16* p) {
  union { u64 u[2]; half8 v; } r;
  r.u[0] = cload64(p);
  r.u[1] = cload64(p + 4);
  return r.v;
}
__device__ inline void cstore_pair(_Float16* p, float a, float b) {
  union { unsigned u; _Float16 h[2]; } pk;
  pk.h[0] = (_Float16)a; pk.h[1] = (_Float16)b;
  __hip_atomic_store((unsigned*)p, pk.u, __ATOMIC_RELAXED, __HIP_MEMORY_SCOPE_AGENT);
}
__device__ inline unsigned poll_llc(const unsigned* p) {
  return __hip_atomic_load(p, __ATOMIC_RELAXED, __HIP_MEMORY_SCOPE_AGENT);
}

// ---- XCD-L2-coherent (sc0) asm accessors ----
__device__ inline unsigned poll_l2(const unsigned* p) {
  unsigned v;
  asm volatile("global_load_dword %0, %1, off sc0\n\ts_waitcnt vmcnt(0)"
               : "=v"(v) : "v"(p) : "memory");
  return v;
}
__device__ inline void st64_l2(void* p, floatx2 v) {
  asm volatile("global_store_dwordx2 %0, %1, off sc0" :: "v"(p), "v"(v) : "memory");
}
__device__ inline void st64_llc(void* p, floatx2 v) {
  asm volatile("global_store_dwordx2 %0, %1, off sc0 sc1" :: "v"(p), "v"(v) : "memory");
}
__device__ inline void st32_l2(void* p, unsigned v) {
  asm volatile("global_store_dword %0, %1, off sc0" :: "v"(p), "v"(v) : "memory");
}
__device__ inline void st32_llc(void* p, unsigned v) {
  asm volatile("global_store_dword %0, %1, off sc0 sc1" :: "v"(p), "v"(v) : "memory");
}
// Batch of 8 sc0 16B loads + one waitcnt in ONE asm block (regs protected).
__device__ inline void ld8_sc0(const void* p0, const void* p1, const void* p2, const void* p3,
                               const void* p4, const void* p5, const void* p6, const void* p7,
                               half8& r0, half8& r1, half8& r2, half8& r3,
                               half8& r4, half8& r5, half8& r6, half8& r7) {
  floatx4 t0, t1, t2, t3, t4, t5, t6, t7;
  asm volatile(
      "global_load_dwordx4 %0, %8, off sc0\n\t"
      "global_load_dwordx4 %1, %9, off sc0\n\t"
      "global_load_dwordx4 %2, %10, off sc0\n\t"
      "global_load_dwordx4 %3, %11, off sc0\n\t"
      "global_load_dwordx4 %4, %12, off sc0\n\t"
      "global_load_dwordx4 %5, %13, off sc0\n\t"
      "global_load_dwordx4 %6, %14, off sc0\n\t"
      "global_load_dwordx4 %7, %15, off sc0\n\t"
      "s_waitcnt vmcnt(0)"
      : "=&v"(t0), "=&v"(t1), "=&v"(t2), "=&v"(t3),
        "=&v"(t4), "=&v"(t5), "=&v"(t6), "=&v"(t7)
      : "v"(p0), "v"(p1), "v"(p2), "v"(p3), "v"(p4), "v"(p5), "v"(p6), "v"(p7)
      : "memory");
  r0 = __builtin_bit_cast(half8, t0); r1 = __builtin_bit_cast(half8, t1);
  r2 = __builtin_bit_cast(half8, t2); r3 = __builtin_bit_cast(half8, t3);
  r4 = __builtin_bit_cast(half8, t4); r5 = __builtin_bit_cast(half8, t5);
  r6 = __builtin_bit_cast(half8, t6); r7 = __builtin_bit_cast(half8, t7);
}

// Wave-parallel wait on flags[lo..hi) with watchdog demotion and sleep backoff.
// Call from threads 0..63 only; caller must __syncthreads() after.
__device__ inline void waitf_range(const unsigned* fl, const unsigned* fg,
                                   volatile int* fastSlot, unsigned tg, int lo, int hi) {
  if (tg == 0) return;
  const int ln = threadIdx.x & 63;
  const bool mine = (ln >= lo) && (ln < hi);
  if (*fastSlot) {
    const unsigned* p = fl + ln * 32;
    for (int it = 0; it < SPIN_BUDGET; ++it) {
      unsigned v = poll_l2(p);
      if (__all((int)(!mine || v >= tg))) return;
      if (it > 16) __builtin_amdgcn_s_sleep(2);
    }
    if (ln == 0) *fastSlot = 0;  // demote forever (liveness guarantee)
  }
  const unsigned* p2 = fg + ln * 32;
  int it2 = 0;
  while (true) {
    unsigned v = poll_llc(p2);
    if (__all((int)(!mine || v >= tg))) return;
    if (++it2 > 32) __builtin_amdgcn_s_sleep(1);
  }
}

__device__ inline half8 cvt8(const float* p) {
  half8 h;
#pragma unroll
  for (int e = 0; e < 8; ++e) h[e] = (_Float16)p[e];
  return h;
}
__device__ inline floatx4 mfma16(half8 a, half8 b, floatx4 c) {
  return __builtin_amdgcn_mfma_f32_16x16x32_f16(a, b, c, 0, 0, 0);
}

// 4 k-chunks (producers 4*CB*4.. ) of the recurrent GEMM, fast (local L2) path.
template <int CB>
__device__ inline void rec4_fast(const char* fb, const half8 (&bR)[2][16],
                                 floatx4 (&acc)[2][2]) {
  const char* b0 = fb + (CB * 4 + 0) * 4096;
  const char* b1 = fb + (CB * 4 + 1) * 4096;
  const char* b2 = fb + (CB * 4 + 2) * 4096;
  const char* b3 = fb + (CB * 4 + 3) * 4096;
  half8 a00, a01, a10, a11, a20, a21, a30, a31;
  ld8_sc0(b0, b0 + 256, b1, b1 + 256, b2, b2 + 256, b3, b3 + 256,
          a00, a01, a10, a11, a20, a21, a30, a31);
#pragma unroll
  for (int i2 = 0; i2 < 4; ++i2) {
    half8 a0v = (i2 == 0) ? a00 : (i2 == 1) ? a10 : (i2 == 2) ? a20 : a30;
    half8 a1v = (i2 == 0) ? a01 : (i2 == 1) ? a11 : (i2 == 2) ? a21 : a31;
    const int c = CB * 4 + i2;
    acc[0][0] = mfma16(a0v, bR[0][c], acc[0][0]);
    acc[0][1] = mfma16(a0v, bR[1][c], acc[0][1]);
    acc[1][0] = mfma16(a1v, bR[0][c], acc[1][0]);
    acc[1][1] = mfma16(a1v, bR[1][c], acc[1][1]);
  }
}
// Same, LLC fallback path.
template <int CB>
__device__ inline void rec4_llc(const _Float16* hb, const half8 (&bR)[2][16],
                                floatx4 (&acc)[2][2]) {
#pragma unroll
  for (int i2 = 0; i2 < 4; ++i2) {
    const int c = CB * 4 + i2;
    half8 a0 = cload_h8(hb + c * 32);
    half8 a1 = cload_h8(hb + 16 * HID + c * 32);
    acc[0][0] = mfma16(a0, bR[0][c], acc[0][0]);
    acc[0][1] = mfma16(a0, bR[1][c], acc[0][1]);
    acc[1][0] = mfma16(a1, bR[0][c], acc[1][0]);
    acc[1][1] = mfma16(a1, bR[1][c], acc[1][1]);
  }
}

__global__ void init_kernel(const float* __restrict__ x, const float* __restrict__ hc,
                            _Float16* __restrict__ x16, _Float16* __restrict__ h0g,
                            _Float16* __restrict__ h1g, unsigned* __restrict__ flagbase) {
  size_t i = (size_t)blockIdx.x * blockDim.x + threadIdx.x;
  size_t stride = (size_t)gridDim.x * blockDim.x;
  const size_t n = (size_t)T_STEPS * 64 * IN_DIM;
  for (size_t idx = i; idx < n; idx += stride) x16[idx] = (_Float16)x[idx];
  if (i < 16384) {
    // h0[-1] -> h0g ring slot 7; h1[-1] -> h1g parity 1 (LLC-coherent stores).
    cstore_pair(h0g + (size_t)(RING - 1) * 32768 + 2 * i, hc[2 * i], hc[2 * i + 1]);
    cstore_pair(h1g + 32768 + 2 * i, hc[32768 + 2 * i], hc[32768 + 2 * i + 1]);
  }
  if (i < 8192) {  // zero all 4 flag arrays (4 x 8192 B contiguous from flags0l)
    __hip_atomic_store(flagbase + i, 0u, __ATOMIC_RELAXED, __HIP_MEMORY_SCOPE_AGENT);
  }
}

// Workers: blockIdx%8==0 -> L0 slice q=blockIdx/8; %8==1 -> L1 slice q. Others exit.
// h/flags dual-written (sc0 local + sc0sc1 LLC). Runtime XCD consensus enables
// the same-L2 fast path; watchdog demotes to LLC on any visibility failure.
// Per-producer flags gate a two-phase rec GEMM (producers 0..31 then 32..63).
__global__ __launch_bounds__(128, 1) void lstm_kernel(
    const _Float16* __restrict__ x16,
    _Float16* __restrict__ h0g, _Float16* __restrict__ h1g,
    _Float16* __restrict__ h0l, _Float16* __restrict__ h1l,
    unsigned* __restrict__ flags0l, unsigned* __restrict__ flags0g,
    unsigned* __restrict__ flags1l, unsigned* __restrict__ flags1g,
    unsigned* __restrict__ prod0, unsigned* __restrict__ prod1,
    const float* __restrict__ W_ih0, const float* __restrict__ W_hh0,
    const float* __restrict__ b_ih0, const float* __restrict__ b_hh0,
    const float* __restrict__ W_ih1, const float* __restrict__ W_hh1,
    const float* __restrict__ b_ih1, const float* __restrict__ b_hh1,
    const float* __restrict__ W_out, const float* __restrict__ b_out,
    const float* __restrict__ hc, float* __restrict__ out) {
  const int r8 = blockIdx.x & 7;
  if (r8 > 1) return;
  const bool isL0 = (r8 == 0);
  const int q = blockIdx.x >> 3;  // 0..63
  const int col0 = q * 8;

  __shared__ __align__(16) _Float16 bAlds[16 * 1280];
  __shared__ float cbuf[64 * 36];
  __shared__ float cstate[512];
  __shared__ float blds[32];
  __shared__ int fastS[2];  // [0]=same-layer fast, [1]=other-layer fast

  unsigned myxcd;
  asm volatile("s_getreg_b32 %0, hwreg(HW_REG_XCC_ID)" : "=s"(myxcd));
  if (threadIdx.x == 0) {
    __hip_atomic_store((isL0 ? prod0 : prod1) + q, myxcd, __ATOMIC_RELAXED,
                       __HIP_MEMORY_SCOPE_AGENT);
    fastS[0] = 0; fastS[1] = 0;
  }

  const int Ka = isL0 ? IN_DIM : HID;
  const int nkA = isL0 ? 8 : 16;
  const float* Wa = isL0 ? W_ih0 : W_ih1;
  const float* Wb = isL0 ? W_hh0 : W_hh1;
  const float* bia = isL0 ? b_ih0 : b_ih1;
  const float* bib = isL0 ? b_hh0 : b_hh1;

  const int lane = threadIdx.x & 63;
  const int wv = threadIdx.x >> 6;   // 0..1
  const int lrow = lane & 15;
  const int kq = (lane >> 4) * 8;
  const int kq8 = lane >> 4;

  // Stage bA fragments into LDS (fp32 -> fp16).
  for (int idx = threadIdx.x; idx < nkA * 128; idx += 128) {
    int c = idx >> 7;
    int rem = idx & 127;
    int col = rem >> 2, kqi = rem & 3;
    int grow = (col >> 3) * HID + col0 + (col & 7);  // PyTorch gate order i,f,g,o
    half8 w = cvt8(Wa + (size_t)grow * Ka + c * 32 + kqi * 8);
    *(half8*)(bAlds + c * 1280 + col * 40 + kqi * 8) = w;
  }
  // Recurrent weights bR -> registers (critical path).
  half8 bR[2][16];
  {
    int g0 = lrow >> 3, j0 = lrow & 7;
    int g1 = (16 + lrow) >> 3, j1 = lrow & 7;
    const float* wb0 = Wb + (size_t)(g0 * HID + col0 + j0) * HID;
    const float* wb1 = Wb + (size_t)(g1 * HID + col0 + j1) * HID;
#pragma unroll
    for (int c = 0; c < 16; ++c) {
      bR[0][c] = cvt8(wb0 + c * 32 + kq);
      bR[1][c] = cvt8(wb1 + c * 32 + kq);
    }
  }
  if (threadIdx.x < 32) {
    int g = threadIdx.x >> 3, j = threadIdx.x & 7;
    blds[threadIdx.x] = bia[g * HID + col0 + j] + bib[g * HID + col0 + j];
  }
  {
    int layer = isL0 ? 0 : 1;
    for (int idx = threadIdx.x; idx < 512; idx += 128) {
      int m = idx >> 3, j = idx & 7;
      cstate[idx] = hc[(size_t)(2 + layer) * 32768 + m * HID + col0 + j];
    }
  }
  __syncthreads();

  const unsigned rowB = (unsigned)(wv * 32 + lrow);  // A-row for mi=0

  for (int t = 0; t < T_STEPS; ++t) {
    floatx4 acc[2][2] = {};  // [mi][nt]

    if (isL0) {
      // ---- x-part (no cross-block dep): compute before any wait ----
      const _Float16* xrow = x16 + (size_t)t * (64 * IN_DIM);
#pragma unroll
      for (int c = 0; c < 8; ++c) {
        half8 a0 = *(const half8*)(xrow + rowB * IN_DIM + c * 32 + kq);
        half8 a1 = *(const half8*)(xrow + (rowB + 16) * IN_DIM + c * 32 + kq);
        half8 b0v = *(const half8*)(bAlds + c * 1280 + lrow * 40 + kq8 * 8);
        half8 b1v = *(const half8*)(bAlds + c * 1280 + (16 + lrow) * 40 + kq8 * 8);
        acc[0][0] = mfma16(a0, b0v, acc[0][0]);
        acc[0][1] = mfma16(a0, b1v, acc[0][1]);
        acc[1][0] = mfma16(a1, b0v, acc[1][0]);
        acc[1][1] = mfma16(a1, b1v, acc[1][1]);
      }
      // ---- phase 1: producers 0..31 ----
      if (threadIdx.x < 64) waitf_range(flags0l, flags0g, &fastS[0], (unsigned)t, 0, 32);
      __syncthreads();
      const char* fb0 = (const char*)h0l + ((unsigned)((t - 1) & 1)) * 65536u +
                        (unsigned)kq8 * 1024u + rowB * 16u;
      const _Float16* hb0 = h0g + (size_t)((t - 1) & 7) * 32768 + rowB * HID + kq;
      if (fastS[0] && t >= 1) { rec4_fast<0>(fb0, bR, acc); rec4_fast<1>(fb0, bR, acc); }
      else                    { rec4_llc<0>(hb0, bR, acc);  rec4_llc<1>(hb0, bR, acc); }
      // ---- phase 2: producers 32..63 (+ ring-free check, slack-filled) ----
      if (threadIdx.x < 64) {
        waitf_range(flags0l, flags0g, &fastS[0], (unsigned)t, 32, 64);
        waitf_range(flags1l, flags1g, &fastS[1],
                    (t >= RING) ? (unsigned)(t - RING + 1) : 0u, 0, 64);
      }
      __syncthreads();
      if (t == 1) {  // own-layer consensus (all L0 flags >=1 => prods stored)
        if (threadIdx.x < 64) {
          int ok = __all((int)(poll_llc(prod0 + lane) == myxcd));
          if (threadIdx.x == 0) fastS[0] = ok;
        }
        __syncthreads();
      }
      if (t == RING) {  // other-layer consensus (first flags1 wait done)
        if (threadIdx.x < 64) {
          int ok = __all((int)(poll_llc(prod1 + lane) == myxcd));
          if (threadIdx.x == 0) fastS[1] = ok;
        }
        __syncthreads();
      }
      if (fastS[0] && t >= 1) { rec4_fast<2>(fb0, bR, acc); rec4_fast<3>(fb0, bR, acc); }
      else                    { rec4_llc<2>(hb0, bR, acc);  rec4_llc<3>(hb0, bR, acc); }
    } else {
      // ---- in-GEMM first: gated by flags0(t+1), ~RING steps of slack ----
      if (threadIdx.x < 64) waitf_range(flags0l, flags0g, &fastS[1], (unsigned)(t + 1), 0, 64);
      __syncthreads();
      {
        const _Float16* hb = h0g + (size_t)(t & 7) * 32768 + rowB * HID + kq;
#pragma unroll
        for (int c = 0; c < 16; ++c) {
          half8 a0 = cload_h8(hb + c * 32);
          half8 a1 = cload_h8(hb + 16 * HID + c * 32);
          half8 b0v = *(const half8*)(bAlds + c * 1280 + lrow * 40 + kq8 * 8);
          half8 b1v = *(const half8*)(bAlds + c * 1280 + (16 + lrow) * 40 + kq8 * 8);
          acc[0][0] = mfma16(a0, b0v, acc[0][0]);
          acc[0][1] = mfma16(a0, b1v, acc[0][1]);
          acc[1][0] = mfma16(a1, b0v, acc[1][0]);
          acc[1][1] = mfma16(a1, b1v, acc[1][1]);
        }
      }
      // ---- tight dep: own-layer peers, two-phase ----
      if (threadIdx.x < 64) waitf_range(flags1l, flags1g, &fastS[0], (unsigned)t, 0, 32);
      __syncthreads();
      const char* fb1 = (const char*)h1l + ((unsigned)((t - 1) & 1)) * 65536u +
                        (unsigned)kq8 * 1024u + rowB * 16u;
      const _Float16* hb1 = h1g + (size_t)((t - 1) & 1) * 32768 + rowB * HID + kq;
      if (fastS[0] && t >= 1) { rec4_fast<0>(fb1, bR, acc); rec4_fast<1>(fb1, bR, acc); }
      else                    { rec4_llc<0>(hb1, bR, acc);  rec4_llc<1>(hb1, bR, acc); }
      if (threadIdx.x < 64) waitf_range(flags1l, flags1g, &fastS[0], (unsigned)t, 32, 64);
      __syncthreads();
      if (t == 1) {  // consensus (flags1 all >=1 and flags0 >=2 => prods stored)
        if (threadIdx.x < 64) {
          int ok1 = __all((int)(poll_llc(prod1 + lane) == myxcd));
          int ok0 = __all((int)(poll_llc(prod0 + lane) == myxcd));
          if (threadIdx.x == 0) { fastS[0] = ok1; fastS[1] = ok0; }
        }
        __syncthreads();
      }
      if (fastS[0] && t >= 1) { rec4_fast<2>(fb1, bR, acc); rec4_fast<3>(fb1, bR, acc); }
      else                    { rec4_llc<2>(hb1, bR, acc);  rec4_llc<3>(hb1, bR, acc); }
    }

    // ---- epilogue: C layout col=lane&15, row=(lane>>4)*4+reg ----
#pragma unroll
    for (int mi = 0; mi < 2; ++mi)
#pragma unroll
      for (int nt = 0; nt < 2; ++nt)
#pragma unroll
        for (int r2 = 0; r2 < 4; ++r2)
          cbuf[(wv * 32 + mi * 16 + (lane >> 4) * 4 + r2) * 36 + nt * 16 + lrow] =
              acc[mi][nt][r2];
    __syncthreads();

    {
      int m = threadIdx.x >> 1;
      int j0 = (threadIdx.x & 1) * 4;
      union { floatx2 f2; _Float16 h[4]; } pk;
#pragma unroll
      for (int jj = 0; jj < 4; ++jj) {
        int j = j0 + jj;
        float xi = cbuf[m * 36 + j] + blds[j];
        float xf = cbuf[m * 36 + 8 + j] + blds[8 + j];
        float xg = cbuf[m * 36 + 16 + j] + blds[16 + j];
        float xo = cbuf[m * 36 + 24 + j] + blds[24 + j];
        float ig = sig_f(xi), fg = sig_f(xf), gg = tanh_f(xg), og = sig_f(xo);
        float c = fg * cstate[m * 8 + j] + ig * gg;
        cstate[m * 8 + j] = c;
        pk.h[jj] = (_Float16)(og * tanh_f(c));
      }
      unsigned par = (unsigned)(t & 1);
      unsigned offL = par * 65536u + (unsigned)q * 1024u + (unsigned)m * 16u + (unsigned)j0 * 2u;
      if (isL0) {
        unsigned offG = (unsigned)(t & 7) * 65536u + (unsigned)(m * 512 + col0 + j0) * 2u;
        st64_l2((char*)h0l + offL, pk.f2);
        st64_llc((char*)h0g + offG, pk.f2);
      } else {
        unsigned offG = par * 65536u + (unsigned)(m * 512 + col0 + j0) * 2u;
        st64_l2((char*)h1l + offL, pk.f2);
        st64_llc((char*)h1g + offG, pk.f2);
      }
    }
    asm volatile("s_waitcnt vmcnt(0)" ::: "memory");
    __syncthreads();
    if (threadIdx.x == 0) {
      unsigned fv = (unsigned)(t + 1);
      unsigned fo = (unsigned)q * 128u;
      if (isL0) { st32_l2((char*)flags0l + fo, fv); st32_llc((char*)flags0g + fo, fv); }
      else      { st32_l2((char*)flags1l + fo, fv); st32_llc((char*)flags1g + fo, fv); }
    }
    asm volatile("" ::: "memory");
  }

  // ---- final linear on L0 blocks: out = h1[511] @ W_out^T + b_out (LLC) ----
  if (isL0) {
    if (threadIdx.x < 64) {
      const unsigned* p = flags1g + lane * 32;
      int it2 = 0;
      while (!__all((int)(poll_llc(p) >= (unsigned)T_STEPS))) {
        if (++it2 > 32) __builtin_amdgcn_s_sleep(1);
      }
    }
    __syncthreads();
    const int m = threadIdx.x >> 1;
    const int oc0 = q * 4 + (threadIdx.x & 1) * 2;
    float s0 = 0.f, s1 = 0.f;
    const float* w0 = W_out + (size_t)oc0 * HID;
    const float* w1 = w0 + HID;
    const _Float16* hrow = h1g + 32768 + m * HID;  // h1[511] at parity 1
#pragma unroll 4
    for (int c = 0; c < 64; ++c) {
      half8 a = cload_h8(hrow + c * 8);
#pragma unroll
      for (int e = 0; e < 8; ++e) {
        float av = (float)a[e];
        s0 += av * w0[c * 8 + e];
        s1 += av * w1[c * 8 + e];
      }
    }
    out[m * 256 + oc0] = s0 + b_out[oc0];
    out[m * 256 + oc0 + 1] = s1 + b_out[oc0 + 1];
  }
}

extern "C" void kernel_launch(void* const* d_in, const int* in_sizes, int n_in,
                              void* d_out, int out_size, void* d_ws, size_t ws_size,
                              hipStream_t stream) {
  const float* x     = (const float*)d_in[0];
  const float* hc    = (const float*)d_in[1];
  const float* W_ih0 = (const float*)d_in[2];
  const float* W_hh0 = (const float*)d_in[3];
  const float* b_ih0 = (const float*)d_in[4];
  const float* b_hh0 = (const float*)d_in[5];
  const float* W_ih1 = (const float*)d_in[6];
  const float* W_hh1 = (const float*)d_in[7];
  const float* b_ih1 = (const float*)d_in[8];
  const float* b_hh1 = (const float*)d_in[9];
  const float* W_out = (const float*)d_in[10];
  const float* b_out = (const float*)d_in[11];
  float* out = (float*)d_out;

  char* ws = (char*)d_ws;
  _Float16* x16 = (_Float16*)ws;                               // 16 MB
  char* p = ws + 16777216;
  _Float16* h0g = (_Float16*)p; p += 8 * 65536;                // 8-slot ring, row-major
  _Float16* h1g = (_Float16*)p; p += 2 * 65536;                // parity, row-major
  _Float16* h0l = (_Float16*)p; p += 2 * 65536;                // parity, slice-major
  _Float16* h1l = (_Float16*)p; p += 2 * 65536;                // parity, slice-major
  unsigned* flags0l = (unsigned*)p; p += 8192;
  unsigned* flags0g = (unsigned*)p; p += 8192;
  unsigned* flags1l = (unsigned*)p; p += 8192;
  unsigned* flags1g = (unsigned*)p; p += 8192;
  unsigned* prod0 = (unsigned*)p; p += 256;
  unsigned* prod1 = (unsigned*)p;

  init_kernel<<<2048, 256, 0, stream>>>(x, hc, x16, h0g, h1g, flags0l);
  lstm_kernel<<<512, 128, 0, stream>>>(x16, h0g, h1g, h0l, h1l,
                                       flags0l, flags0g, flags1l, flags1g,
                                       prod0, prod1,
                                       W_ih0, W_hh0, b_ih0, b_hh0,
                                       W_ih1, W_hh1, b_ih1, b_hh1,
                                       W_out, b_out, hc, out);
}

// Round 9
// 3101.337 us; speedup vs baseline: 1.7835x; 1.7835x over previous
//
#include <hip/hip_runtime.h>

typedef _Float16 half8 __attribute__((ext_vector_type(8)));
typedef float floatx4 __attribute__((ext_vector_type(4)));
typedef unsigned long long u64;

#define T_STEPS 512
#define IN_DIM 256
#define HID 512
#define RING 8

__device__ inline float sig_f(float x) { return 1.f / (1.f + __expf(-x)); }
__device__ inline float tanh_f(float x) {
  float t = __expf(-2.f * fabsf(x));
  return copysignf((1.f - t) / (1.f + t), x);
}

// ---- LLC-coherent (agent-scope) scalar accessors — proven in R3 ----
__device__ inline void cstore_pair(_Float16* p, float a, float b) {
  union { unsigned u; _Float16 h[2]; } pk;
  pk.h[0] = (_Float16)a; pk.h[1] = (_Float16)b;
  __hip_atomic_store((unsigned*)p, pk.u, __ATOMIC_RELAXED, __HIP_MEMORY_SCOPE_AGENT);
}
__device__ inline unsigned poll_llc(const unsigned* p) {
  return __hip_atomic_load(p, __ATOMIC_RELAXED, __HIP_MEMORY_SCOPE_AGENT);
}
__device__ inline u64 cload64(const _Float16* p) {
  return __hip_atomic_load((const u64*)p, __ATOMIC_RELAXED, __HIP_MEMORY_SCOPE_AGENT);
}
__device__ inline half8 cload_h8(const _Float16* p) {
  union { u64 u[2]; half8 v; } r;
  r.u[0] = cload64(p);
  r.u[1] = cload64(p + 4);
  return r.v;
}

// ---- THE KEY CHANGE: batched LLC loads. 8x16B from one base (offsets are
// immediates, 64B stride) + ONE waitcnt, all inside a single asm block so the
// 16 serialized RTTs of the old atomic-load loop become ~1 pipelined RTT.
__device__ inline void ld8_llc(const _Float16* base, half8 (&r)[8]) {
  floatx4 t0, t1, t2, t3, t4, t5, t6, t7;
  asm volatile(
      "global_load_dwordx4 %0, %8, off sc0 sc1\n\t"
      "global_load_dwordx4 %1, %8, off offset:64 sc0 sc1\n\t"
      "global_load_dwordx4 %2, %8, off offset:128 sc0 sc1\n\t"
      "global_load_dwordx4 %3, %8, off offset:192 sc0 sc1\n\t"
      "global_load_dwordx4 %4, %8, off offset:256 sc0 sc1\n\t"
      "global_load_dwordx4 %5, %8, off offset:320 sc0 sc1\n\t"
      "global_load_dwordx4 %6, %8, off offset:384 sc0 sc1\n\t"
      "global_load_dwordx4 %7, %8, off offset:448 sc0 sc1\n\t"
      "s_waitcnt vmcnt(0)"
      : "=&v"(t0), "=&v"(t1), "=&v"(t2), "=&v"(t3),
        "=&v"(t4), "=&v"(t5), "=&v"(t6), "=&v"(t7)
      : "v"(base)
      : "memory");
  r[0] = __builtin_bit_cast(half8, t0); r[1] = __builtin_bit_cast(half8, t1);
  r[2] = __builtin_bit_cast(half8, t2); r[3] = __builtin_bit_cast(half8, t3);
  r[4] = __builtin_bit_cast(half8, t4); r[5] = __builtin_bit_cast(half8, t5);
  r[6] = __builtin_bit_cast(half8, t6); r[7] = __builtin_bit_cast(half8, t7);
}

// Wave-parallel wait on 64 flags (call from one full wave; others at barrier).
__device__ inline void waitf(const unsigned* fg, unsigned tg) {
  if (tg == 0) return;
  const unsigned* p = fg + (threadIdx.x & 63) * 32;
  int it = 0;
  while (!__all((int)(poll_llc(p) >= tg))) {
    if (++it > 4) __builtin_amdgcn_s_sleep(1);
  }
}

__device__ inline floatx4 mfma16(half8 a, half8 b, floatx4 c) {
  return __builtin_amdgcn_mfma_f32_16x16x32_f16(a, b, c, 0, 0, 0);
}

__global__ void init_kernel(const float* __restrict__ x, const float* __restrict__ hc,
                            _Float16* __restrict__ x16, _Float16* __restrict__ h0b,
                            _Float16* __restrict__ h1b, unsigned* __restrict__ flagbase) {
  size_t i = (size_t)blockIdx.x * blockDim.x + threadIdx.x;
  size_t stride = (size_t)gridDim.x * blockDim.x;
  const size_t n = (size_t)T_STEPS * 64 * IN_DIM;
  for (size_t idx = i; idx < n; idx += stride) x16[idx] = (_Float16)x[idx];
  if (i < 16384) {
    // h0[-1] -> ring slot 7; h1[-1] -> parity 1 (LLC-coherent stores).
    cstore_pair(h0b + (size_t)(RING - 1) * 32768 + 2 * i, hc[2 * i], hc[2 * i + 1]);
    cstore_pair(h1b + 32768 + 2 * i, hc[32768 + 2 * i], hc[32768 + 2 * i + 1]);
  }
  if (i < 4096) {  // zero both flag arrays (2 x 8192 B contiguous)
    __hip_atomic_store(flagbase + i, 0u, __ATOMIC_RELAXED, __HIP_MEMORY_SCOPE_AGENT);
  }
}

// R3 skeleton: blocks 0..63 = L0 (8 h-cols each), 64..127 = L1. Per-layer flag
// arrays, one-way L0->L1 dep, 8-deep h0 ring, LLC coherence only. Change vs R3:
// batched pipelined h loads (ld8_llc) and parallel-wave merged waits.
__global__ __launch_bounds__(256) void lstm_kernel(
    const _Float16* __restrict__ x16, _Float16* __restrict__ h0b, _Float16* __restrict__ h1b,
    unsigned* __restrict__ flags0, unsigned* __restrict__ flags1,
    const float* __restrict__ W_ih0, const float* __restrict__ W_hh0,
    const float* __restrict__ b_ih0, const float* __restrict__ b_hh0,
    const float* __restrict__ W_ih1, const float* __restrict__ W_hh1,
    const float* __restrict__ b_ih1, const float* __restrict__ b_hh1,
    const float* __restrict__ W_out, const float* __restrict__ b_out,
    const float* __restrict__ hc, float* __restrict__ out) {
  __shared__ __align__(16) _Float16 wlds[32 * 1032];
  __shared__ float cbuf[64 * 36];
  __shared__ float cstate[512];
  __shared__ float blds[32];

  const int bq = blockIdx.x;
  const bool isL0 = bq < 64;
  const int q = isL0 ? bq : bq - 64;
  const int col0 = q * 8;
  const int Ka = isL0 ? IN_DIM : HID;
  const int K = Ka + HID;
  const int WP = K + 8;
  const float* Wa = isL0 ? W_ih0 : W_ih1;
  const float* Wb = isL0 ? W_hh0 : W_hh1;
  const float* bia = isL0 ? b_ih0 : b_ih1;
  const float* bib = isL0 ? b_hh0 : b_hh1;
  unsigned* myflag = (isL0 ? flags0 : flags1) + q * 32;

  for (int idx = threadIdx.x; idx < 32 * K; idx += 256) {
    int r = idx / K;
    int k = idx - r * K;
    int g = r >> 3, j = r & 7;
    int grow = g * HID + col0 + j;  // PyTorch gate order i,f,g,o
    float w = (k < Ka) ? Wa[(size_t)grow * Ka + k] : Wb[(size_t)grow * HID + (k - Ka)];
    wlds[r * WP + k] = (_Float16)w;
  }
  if (threadIdx.x < 32) {
    int g = threadIdx.x >> 3, j = threadIdx.x & 7;
    int grow = g * HID + col0 + j;
    blds[threadIdx.x] = bia[grow] + bib[grow];
  }
  {
    int layer = isL0 ? 0 : 1;
    for (int idx = threadIdx.x; idx < 512; idx += 256) {
      int m = idx >> 3, j = idx & 7;
      cstate[idx] = hc[(size_t)(2 + layer) * 32768 + m * HID + col0 + j];
    }
  }
  __syncthreads();

  const int lane = threadIdx.x & 63;
  const int wv = threadIdx.x >> 6;   // 0..3
  const int lrow = lane & 15;
  const int kq = (lane >> 4) * 8;
  const int m0 = wv * 16;
  const _Float16* wrow0 = wlds + lrow * WP;
  const _Float16* wrow1 = wlds + (16 + lrow) * WP;

  // Recurrent-half B fragments in registers (proven in R2/R3).
  half8 breg0[16], breg1[16];
#pragma unroll
  for (int c = 0; c < 16; ++c) {
    breg0[c] = *(const half8*)(wrow0 + Ka + c * 32 + kq);
    breg1[c] = *(const half8*)(wrow1 + Ka + c * 32 + kq);
  }

  const int gm = threadIdx.x >> 2;
  const int gj = (threadIdx.x & 3) * 2;

  for (int t = 0; t < T_STEPS; ++t) {
    floatx4 acc0 = {0.f, 0.f, 0.f, 0.f};
    floatx4 acc1 = {0.f, 0.f, 0.f, 0.f};
    _Float16* dst;
    half8 av[8];

    if (isL0) {
      // X phase (no cross-block dep): compute before the wait.
      const _Float16* a0p = x16 + (size_t)t * (64 * IN_DIM) + (m0 + lrow) * IN_DIM + kq;
#pragma unroll
      for (int c = 0; c < 8; ++c) {
        half8 a = *(const half8*)(a0p + c * 32);
        half8 b0v = *(const half8*)(wrow0 + c * 32 + kq);
        half8 b1v = *(const half8*)(wrow1 + c * 32 + kq);
        acc0 = mfma16(a, b0v, acc0);
        acc1 = mfma16(a, b1v, acc1);
      }
      // Merged wait: wave0 -> peers' h0[t-1]; wave1 -> ring slot free.
      if (threadIdx.x < 64) waitf(flags0, (unsigned)t);
      else if (threadIdx.x < 128) waitf(flags1, (t >= RING) ? (unsigned)(t - RING + 1) : 0u);
      __syncthreads();
      asm volatile("" ::: "memory");
      const _Float16* a1p = h0b + (size_t)((t - 1) & (RING - 1)) * 32768 + (m0 + lrow) * HID + kq;
      ld8_llc(a1p, av);
#pragma unroll
      for (int c = 0; c < 8; ++c) {
        acc0 = mfma16(av[c], breg0[c], acc0);
        acc1 = mfma16(av[c], breg1[c], acc1);
      }
      ld8_llc(a1p + 256, av);
#pragma unroll
      for (int c = 0; c < 8; ++c) {
        acc0 = mfma16(av[c], breg0[8 + c], acc0);
        acc1 = mfma16(av[c], breg1[8 + c], acc1);
      }
      dst = h0b + (size_t)(t & (RING - 1)) * 32768;
    } else {
      if (threadIdx.x < 64) waitf(flags0, (unsigned)(t + 1));  // h0[t] ready
      __syncthreads();
      asm volatile("" ::: "memory");
      const _Float16* a0p = h0b + (size_t)(t & (RING - 1)) * 32768 + (m0 + lrow) * HID + kq;
      ld8_llc(a0p, av);
#pragma unroll
      for (int c = 0; c < 8; ++c) {
        half8 b0v = *(const half8*)(wrow0 + c * 32 + kq);
        half8 b1v = *(const half8*)(wrow1 + c * 32 + kq);
        acc0 = mfma16(av[c], b0v, acc0);
        acc1 = mfma16(av[c], b1v, acc1);
      }
      ld8_llc(a0p + 256, av);
#pragma unroll
      for (int c = 0; c < 8; ++c) {
        half8 b0v = *(const half8*)(wrow0 + (8 + c) * 32 + kq);
        half8 b1v = *(const half8*)(wrow1 + (8 + c) * 32 + kq);
        acc0 = mfma16(av[c], b0v, acc0);
        acc1 = mfma16(av[c], b1v, acc1);
      }
      if (threadIdx.x < 64) waitf(flags1, (unsigned)t);  // peers' h1[t-1]
      __syncthreads();
      asm volatile("" ::: "memory");
      const _Float16* a1p = h1b + (size_t)((t - 1) & 1) * 32768 + (m0 + lrow) * HID + kq;
      ld8_llc(a1p, av);
#pragma unroll
      for (int c = 0; c < 8; ++c) {
        acc0 = mfma16(av[c], breg0[c], acc0);
        acc1 = mfma16(av[c], breg1[c], acc1);
      }
      ld8_llc(a1p + 256, av);
#pragma unroll
      for (int c = 0; c < 8; ++c) {
        acc0 = mfma16(av[c], breg0[8 + c], acc0);
        acc1 = mfma16(av[c], breg1[8 + c], acc1);
      }
      dst = h1b + (size_t)(t & 1) * 32768;
    }

    // C/D layout: col = lane&15 (gate row), row = (lane>>4)*4 + reg (batch)
    const int mrow = m0 + (lane >> 4) * 4;
#pragma unroll
    for (int r2 = 0; r2 < 4; ++r2) {
      cbuf[(mrow + r2) * 36 + lrow] = acc0[r2];
      cbuf[(mrow + r2) * 36 + 16 + lrow] = acc1[r2];
    }
    __syncthreads();

    float hv[2];
#pragma unroll
    for (int e = 0; e < 2; ++e) {
      int j = gj + e;
      float xi = cbuf[gm * 36 + j] + blds[j];
      float xf = cbuf[gm * 36 + 8 + j] + blds[8 + j];
      float xg = cbuf[gm * 36 + 16 + j] + blds[16 + j];
      float xo = cbuf[gm * 36 + 24 + j] + blds[24 + j];
      float ig = sig_f(xi), fg = sig_f(xf), gg = tanh_f(xg), og = sig_f(xo);
      float c = fg * cstate[gm * 8 + j] + ig * gg;
      cstate[gm * 8 + j] = c;
      hv[e] = og * tanh_f(c);
    }
    cstore_pair(dst + gm * HID + col0 + gj, hv[0], hv[1]);

    // Release: drain stores, join block, one flag store.
    asm volatile("s_waitcnt vmcnt(0)" ::: "memory");
    __syncthreads();
    if (threadIdx.x == 0) {
      __hip_atomic_store(myflag, (unsigned)(t + 1), __ATOMIC_RELAXED, __HIP_MEMORY_SCOPE_AGENT);
    }
    asm volatile("" ::: "memory");
  }

  // Final linear on L0 blocks: out[64,256] = h1[511] @ W_out^T + b_out.
  if (isL0) {
    if (threadIdx.x < 64) waitf(flags1, (unsigned)T_STEPS);
    __syncthreads();
    asm volatile("" ::: "memory");
    const int oc = q * 4 + (threadIdx.x & 3);
    const int m = threadIdx.x >> 2;
    const _Float16* hrow = h1b + 32768 + m * HID;  // h1[511] at parity 1
    const float* wrow = W_out + (size_t)oc * HID;
    float sum = 0.f;
#pragma unroll 4
    for (int h = 0; h < HID; h += 8) {
      half8 hvv = cload_h8(hrow + h);
#pragma unroll
      for (int e = 0; e < 8; ++e) sum += (float)hvv[e] * wrow[h + e];
    }
    out[m * 256 + oc] = sum + b_out[oc];
  }
}

extern "C" void kernel_launch(void* const* d_in, const int* in_sizes, int n_in,
                              void* d_out, int out_size, void* d_ws, size_t ws_size,
                              hipStream_t stream) {
  const float* x     = (const float*)d_in[0];
  const float* hc    = (const float*)d_in[1];
  const float* W_ih0 = (const float*)d_in[2];
  const float* W_hh0 = (const float*)d_in[3];
  const float* b_ih0 = (const float*)d_in[4];
  const float* b_hh0 = (const float*)d_in[5];
  const float* W_ih1 = (const float*)d_in[6];
  const float* W_hh1 = (const float*)d_in[7];
  const float* b_ih1 = (const float*)d_in[8];
  const float* b_hh1 = (const float*)d_in[9];
  const float* W_out = (const float*)d_in[10];
  const float* b_out = (const float*)d_in[11];
  float* out = (float*)d_out;

  char* ws = (char*)d_ws;
  _Float16* x16 = (_Float16*)ws;                              // 16 MB
  _Float16* h0b = (_Float16*)(ws + 16777216);                 // 8 x 64 KB ring
  _Float16* h1b = (_Float16*)(ws + 16777216 + 8 * 65536);     // 2 x 64 KB
  unsigned* flags0 = (unsigned*)(ws + 16777216 + 10 * 65536);           // 64 x 128 B
  unsigned* flags1 = (unsigned*)(ws + 16777216 + 10 * 65536 + 8192);    // 64 x 128 B

  init_kernel<<<2048, 256, 0, stream>>>(x, hc, x16, h0b, h1b, flags0);
  lstm_kernel<<<128, 256, 0, stream>>>(x16, h0b, h1b, flags0, flags1,
                                       W_ih0, W_hh0, b_ih0, b_hh0,
                                       W_ih1, W_hh1, b_ih1, b_hh1,
                                       W_out, b_out, hc, out);
}